// Round 7
// baseline (385.881 us; speedup 1.0000x reference)
//
#include <hip/hip_runtime.h>
#include <hip/hip_bf16.h>
#include <cmath>

// Problem constants
#define B_    4
#define T_    1000000
#define E_    8
#define C_    128
#define NCH   512        // fused conv output channels (both branches, 2*256)
#define KK    4096       // GEMM K = E * kernel (8*512); windows are contiguous rows
#define TOUT  1953       // (1e6 - 512)/512 + 1
#define TP    1956       // padded t stride (mult of 4) for aligned float4 stores
#define NT2   31         // ceil(1953/64) tiles of 64 along t

typedef __attribute__((ext_vector_type(8))) short bf16x8;   // 8 bf16 = 4 VGPRs
typedef __attribute__((ext_vector_type(4))) float f32x4;

__device__ __forceinline__ float sigmoidf_(float v) { return 1.f / (1.f + __expf(-v)); }

// ---------------------------------------------------------------------------
// Fragment-ordered B layout ("frag chunk" = 16 n-rows x 32 k, stored [lane][8]
// in exact MFMA B-operand order: lane = (k>>3 & 3)*16 + (n&15), j = k&7).
// One chunk = 512 elems = 1KB; a fragment load = ONE coalesced dwordx4/lane.
// Wn2: [nt=n/16][kc=k/32][lane][8]
//
// Kernel B: weight prep. (o,e,kpos) -> frag-ordered bf16, k = kpos*8+e.
__global__ __launch_bounds__(256) void prep_w(
    const float* __restrict__ wc, const float* __restrict__ bc,
    const float* __restrict__ wm, const float* __restrict__ bm,
    __hip_bfloat16* __restrict__ Wn2, float* __restrict__ bias_t) {
  __shared__ float row[KK];
  const int n = blockIdx.x, br = n >> 8, o = n & 255;
  const float* wsrc = (br ? wm : wc) + (size_t)o * KK;
  for (int i = threadIdx.x; i < KK; i += 256) row[i] = wsrc[i];   // [e][kpos]
  __syncthreads();
  const int nt = n >> 4, nr = n & 15;
  for (int k = threadIdx.x; k < KK; k += 256) {
    int kpos = k >> 3, e = k & 7;                 // W[n][k] with k = kpos*8+e
    size_t addr = (((size_t)nt * 128 + (k >> 5)) * 64
                   + (size_t)((k >> 3) & 3) * 16 + nr) * 8 + (k & 7);
    Wn2[addr] = __float2bfloat16(row[e * 512 + kpos]);
  }
  if (threadIdx.x == 0) bias_t[n] = (br ? bm : bc)[o];
}

// ---------------------------------------------------------------------------
// Kernel C: barrier-free, LDS-free register GEMM with fused fp32->bf16 A
// conversion. C[t,n] = sum_k A[t,k]W[n,k]. Block = 512 thr = 8 waves
// (4 t-waves x 2 n-waves), block tile 128x128, wave tile 32t x 64n.
// A fragments are loaded DIRECTLY from fp32 x: the MFMA A-operand wants
// lane (kq*16 + t&15) to hold A[t][k..k+7] -> 8 consecutive floats = two
// dwordx4 per lane; cvt to bf16 in regs right before the MFMA (same rounding
// as the old convert pass). B from frag-ordered Wn2 (1 dwordx4 per frag).
// Two register sets ping-pong; no __syncthreads in the loop. Grid 256 =
// 1 block/CU; XCD swizzle: 4 n-groups of one (t,b) share L%8 = XCD so fp32
// A re-reads hit that XCD's L2 (R4 proof: FETCH 254->82MB).
__global__ __launch_bounds__(512, 2) void mfma_gemm(
    const float* __restrict__ x, const __hip_bfloat16* __restrict__ Wn2,
    float* __restrict__ u2) {
  const int tid  = threadIdx.x;
  const int lane = tid & 63, wave = tid >> 6;
  const int wt = wave & 3, wn = wave >> 2;

  // Swizzle: L = xcd + 8*(nb + 4*sh); s = sh*8 + xcd = (t,b) group 0..63.
  const int L   = blockIdx.x;
  const int xcd = L & 7;
  const int r   = L >> 3;
  const int nb  = r & 3;
  const int sh  = r >> 2;                 // 0..7
  const int s   = sh * 8 + xcd;           // 0..63
  const int tblk = s & 15, b = s >> 4;
  const int t0 = tblk * 128, n0 = nb * 128;

  // Per-lane fp32 A row bases for the two row-fragments (i=0,1), clamped to
  // the last valid window (clamped rows produce finite garbage that lands in
  // the u2 pad region or is skipped at store).
  const int ta = t0 + wt * 32 + (lane & 15);
  const int rA0 = (ta      < TOUT) ? ta      : (TOUT - 1);
  const int rA1 = (ta + 16 < TOUT) ? ta + 16 : (TOUT - 1);
  const float* aB0 = x + (size_t)b * 8000000ull + (size_t)rA0 * KK + ((lane >> 4) * 8);
  const float* aB1 = x + (size_t)b * 8000000ull + (size_t)rA1 * KK + ((lane >> 4) * 8);

  const size_t FR = 512;                  // elems per B frag chunk
  const __hip_bfloat16* bB = Wn2
      + ((size_t)((n0 >> 4) + wn * 4) * 128) * FR + (size_t)lane * 8;
  // B frag (j,kc) at bB + (j*128+kc)*FR

  f32x4 acc[2][4];
#pragma unroll
  for (int i = 0; i < 2; ++i)
#pragma unroll
    for (int j = 0; j < 4; ++j) acc[i][j] = (f32x4)(0.0f);

  // A fp32 raw: [i][c][half]; B bf16 frags: [j][c]   (c = kc chunk within set)
  f32x4 A0[2][2][2], A1[2][2][2];
  bf16x8 B0[4][2], B1[4][2];

  auto load_set = [&](f32x4 (&aF)[2][2][2], bf16x8 (&bF)[4][2], int kc) {
#pragma unroll
    for (int c = 0; c < 2; ++c) {
      const float* p0 = aB0 + (size_t)(kc + c) * 32;
      const float* p1 = aB1 + (size_t)(kc + c) * 32;
      aF[0][c][0] = *(const f32x4*)(p0);
      aF[0][c][1] = *(const f32x4*)(p0 + 4);
      aF[1][c][0] = *(const f32x4*)(p1);
      aF[1][c][1] = *(const f32x4*)(p1 + 4);
    }
#pragma unroll
    for (int j = 0; j < 4; ++j)
#pragma unroll
      for (int c = 0; c < 2; ++c)
        bF[j][c] = *(const bf16x8*)(bB + (size_t)(j * 128 + kc + c) * FR);
  };
  auto cvt8 = [](const f32x4& lo, const f32x4& hi) -> bf16x8 {
    union { __hip_bfloat16 h[8]; bf16x8 v; } u;
    u.h[0] = __float2bfloat16(lo.x); u.h[1] = __float2bfloat16(lo.y);
    u.h[2] = __float2bfloat16(lo.z); u.h[3] = __float2bfloat16(lo.w);
    u.h[4] = __float2bfloat16(hi.x); u.h[5] = __float2bfloat16(hi.y);
    u.h[6] = __float2bfloat16(hi.z); u.h[7] = __float2bfloat16(hi.w);
    return u.v;
  };
  auto do_mfma = [&](f32x4 (&aF)[2][2][2], bf16x8 (&bF)[4][2]) {
#pragma unroll
    for (int c = 0; c < 2; ++c) {
      bf16x8 a0 = cvt8(aF[0][c][0], aF[0][c][1]);
      bf16x8 a1 = cvt8(aF[1][c][0], aF[1][c][1]);
#pragma unroll
      for (int j = 0; j < 4; ++j) {
        acc[0][j] = __builtin_amdgcn_mfma_f32_16x16x32_bf16(a0, bF[j][c], acc[0][j], 0, 0, 0);
        acc[1][j] = __builtin_amdgcn_mfma_f32_16x16x32_bf16(a1, bF[j][c], acc[1][j], 0, 0, 0);
      }
    }
  };

  load_set(A0, B0, 0);
  for (int kc = 0; kc < 128; kc += 4) {
    load_set(A1, B1, kc + 2);
    do_mfma(A0, B0);
    if (kc + 4 < 128) load_set(A0, B0, kc + 4);
    do_mfma(A1, B1);
  }

  // Epilogue. C/D layout: col = lane&15, row = (lane>>4)*4 + reg.
  const int crow = (lane >> 4) * 4;
  const int ccol = lane & 15;
#pragma unroll
  for (int j = 0; j < 4; ++j) {
    int n = n0 + wn * 64 + j * 16 + ccol;
    float* urow = u2 + ((size_t)n * B_ + b) * TP;
#pragma unroll
    for (int i = 0; i < 2; ++i) {
      int t = t0 + wt * 32 + i * 16 + crow;    // mult of 4
      if (t < TOUT) *(f32x4*)(urow + t) = acc[i][j];  // may touch pad [1953,1956)
    }
  }
}

// ---------------------------------------------------------------------------
// Kernel 2: bias + GLU (on load from u2) -> 1x1 share conv + leaky.
// br==1: store h_main; br==0: per-tile max over t -> gct_part.
__global__ __launch_bounds__(256) void share_act(
    const float* __restrict__ u2, const float* __restrict__ bias_t,
    const float* __restrict__ wsc, const float* __restrict__ bsc,
    const float* __restrict__ wsm, const float* __restrict__ bsm,
    float* __restrict__ hmain, float* __restrict__ gct_part) {
  __shared__ float Wl[128 * 132];   // Wl[cp*132 + cout] = ws[cout, cp]
  __shared__ float ul[128 * 68];    // ul[cp*68 + t]
  const int tid  = threadIdx.x;
  const int tile = blockIdx.x;      // 0..30
  const int b    = blockIdx.y;
  const int br   = blockIdx.z;
  const int t0   = tile * 64;
  const float* ws = br ? wsm : wsc;
  const float* bs = br ? bsm : bsc;

  for (int g = tid; g < 16384; g += 256) {
    int co = g >> 7, cp = g & 127;
    Wl[cp * 132 + co] = ws[g];
  }
  const size_t base_v = ((size_t)(br * 256) * B_ + b) * TP;
  const size_t base_g = ((size_t)(br * 256 + 128) * B_ + b) * TP;
  for (int g = tid; g < 8192; g += 256) {
    int cp = g >> 6, t = g & 63;
    float v = 0.f;
    if (t0 + t < TOUT) {
      float va = u2[base_v + (size_t)cp * B_ * TP + t0 + t] + bias_t[br * 256 + cp];
      float vg = u2[base_g + (size_t)cp * B_ * TP + t0 + t] + bias_t[br * 256 + 128 + cp];
      v = va * sigmoidf_(vg);
    }
    ul[cp * 68 + t] = v;
  }
  __syncthreads();

  const int ty = tid >> 4, tx = tid & 15;  // c-groups x t-groups
  float acc[8][4];
#pragma unroll
  for (int i = 0; i < 8; ++i)
#pragma unroll
    for (int j = 0; j < 4; ++j) acc[i][j] = 0.f;

  for (int cp = 0; cp < 128; ++cp) {
    float4 a0 = *(const float4*)&Wl[cp*132 + ty*4];
    float4 a1 = *(const float4*)&Wl[cp*132 + 64 + ty*4];
    float4 b4 = *(const float4*)&ul[cp*68 + tx*4];
    float av[8] = {a0.x,a0.y,a0.z,a0.w,a1.x,a1.y,a1.z,a1.w};
    float bv[4] = {b4.x,b4.y,b4.z,b4.w};
#pragma unroll
    for (int i = 0; i < 8; ++i)
#pragma unroll
      for (int j = 0; j < 4; ++j) acc[i][j] = fmaf(av[i], bv[j], acc[i][j]);
  }

  float mloc[8];
#pragma unroll
  for (int i = 0; i < 8; ++i) mloc[i] = -INFINITY;
#pragma unroll
  for (int i = 0; i < 8; ++i) {
    int c = (i < 4) ? (ty*4 + i) : (64 + ty*4 + (i - 4));
    float bias = bs[c];
#pragma unroll
    for (int j = 0; j < 4; ++j) {
      int t = t0 + tx*4 + j;
      if (t >= TOUT) continue;
      float v = acc[i][j] + bias;
      v = (v >= 0.f) ? v : 0.01f * v;
      if (br == 1) {
        hmain[((size_t)b * 128 + c) * TOUT + t] = v;
      } else {
        mloc[i] = fmaxf(mloc[i], v);
      }
    }
  }
  if (br == 0) {
    __syncthreads();               // done reading ul; reuse as reduction buffer
    float* red = ul;               // 128*16 region
#pragma unroll
    for (int i = 0; i < 8; ++i) {
      int c = (i < 4) ? (ty*4 + i) : (64 + ty*4 + (i - 4));
      red[c * 16 + tx] = mloc[i];
    }
    __syncthreads();
    if (tid < 128) {
      float m = -INFINITY;
#pragma unroll
      for (int k = 0; k < 16; ++k) m = fmaxf(m, red[tid * 16 + k]);
      gct_part[((size_t)b * 128 + tid) * NT2 + tile] = m;
    }
  }
}

// ---------------------------------------------------------------------------
// Kernel 3: gct = max over tiles; q = tanh(gct @ Wp^T + bp). One block per b.
__global__ void gct_q(const float* __restrict__ gct_part, const float* __restrict__ wp,
                      const float* __restrict__ bp, float* __restrict__ q) {
  int b = blockIdx.x, tid = threadIdx.x;   // 128 threads
  __shared__ float g[128];
  float m = -INFINITY;
  for (int tl = 0; tl < NT2; ++tl) m = fmaxf(m, gct_part[((size_t)b * 128 + tid) * NT2 + tl]);
  g[tid] = m;
  __syncthreads();
  float s = bp[tid];
  for (int c = 0; c < 128; ++c) s = fmaf(g[c], wp[tid * 128 + c], s);
  q[b * 128 + tid] = tanhf(s);
}

// ---------------------------------------------------------------------------
// Kernel 4: gate[t] = sigmoid(sum_c h*q); out_part = per-tile max_t h*gate.
__global__ __launch_bounds__(256) void gate_max(
    const float* __restrict__ hmain, const float* __restrict__ q,
    float* __restrict__ out_part) {
  __shared__ float hl[128 * 68];
  __shared__ float ql[128];
  __shared__ float red[256];
  __shared__ float gl[64];
  int tid = threadIdx.x, tile = blockIdx.x, b = blockIdx.y;
  int t0 = tile * 64;
  for (int g = tid; g < 8192; g += 256) {
    int c = g >> 6, t = g & 63;
    hl[c * 68 + t] = (t0 + t < TOUT) ? hmain[((size_t)b * 128 + c) * TOUT + t0 + t] : 0.f;
  }
  if (tid < 128) ql[tid] = q[b * 128 + tid];
  __syncthreads();
  {
    int t = tid & 63, cy = tid >> 6;
    float s = 0.f;
#pragma unroll
    for (int cc = 0; cc < 32; ++cc) s = fmaf(hl[(cy * 32 + cc) * 68 + t], ql[cy * 32 + cc], s);
    red[cy * 64 + t] = s;
  }
  __syncthreads();
  if (tid < 64) {
    float s = red[tid] + red[64 + tid] + red[128 + tid] + red[192 + tid];
    gl[tid] = sigmoidf_(s);
  }
  __syncthreads();
  {
    int c = tid >> 1, th = tid & 1;
    float m = -INFINITY;
#pragma unroll
    for (int tt = 0; tt < 32; ++tt) {
      int t = th * 32 + tt;
      if (t0 + t < TOUT) m = fmaxf(m, hl[c * 68 + t] * gl[t]);
    }
    red[c * 2 + th] = m;
  }
  __syncthreads();
  if (tid < 128) out_part[((size_t)b * 128 + tid) * NT2 + tile] = fmaxf(red[tid * 2], red[tid * 2 + 1]);
}

// ---------------------------------------------------------------------------
// Kernel 5: final max over tiles -> d_out (B,C) row-major.
__global__ void final_max(const float* __restrict__ out_part, float* __restrict__ out) {
  int idx = blockIdx.x * 256 + threadIdx.x;
  if (idx < 512) {
    float m = -INFINITY;
    for (int tl = 0; tl < NT2; ++tl) m = fmaxf(m, out_part[(size_t)idx * NT2 + tl]);
    out[idx] = m;
  }
}

// ---------------------------------------------------------------------------
extern "C" void kernel_launch(void* const* d_in, const int* in_sizes, int n_in,
                              void* d_out, int out_size, void* d_ws, size_t ws_size,
                              hipStream_t stream) {
  const float* x      = (const float*)d_in[0];
  const float* ctx_w  = (const float*)d_in[1];
  const float* ctx_b  = (const float*)d_in[2];
  const float* ctx_sw = (const float*)d_in[3];
  const float* ctx_sb = (const float*)d_in[4];
  const float* main_w = (const float*)d_in[5];
  const float* main_b = (const float*)d_in[6];
  const float* main_sw= (const float*)d_in[7];
  const float* main_sb= (const float*)d_in[8];
  const float* gp_w   = (const float*)d_in[9];
  const float* gp_b   = (const float*)d_in[10];

  char* w = (char*)d_ws;
  __hip_bfloat16* Wn2 = (__hip_bfloat16*)(w);              // 512*4096*2 = 4,194,304
  float* bias_t  = (float*)(w + 4194304);                  // 512*4
  float* u2      = (float*)(w + 4196352);                  // 512*4*TP*4 = 16,023,552
  float* hmain   = (float*)(w + 20219904);                 // 4*128*1953*4 = 3,999,744
  float* gct_part= (float*)(w + 24219648);                 // 4*128*31*4 = 63,488
  float* q       = (float*)(w + 24283136);                 // 512*4
  float* out_part= (float*)(w + 24285184);                 // 63,488

  prep_w<<<NCH, 256, 0, stream>>>(ctx_w, ctx_b, main_w, main_b, Wn2, bias_t);
  mfma_gemm<<<256, 512, 0, stream>>>(x, Wn2, u2);
  share_act<<<dim3(NT2, B_, 2), 256, 0, stream>>>(u2, bias_t, ctx_sw, ctx_sb,
                                                  main_sw, main_sb, hmain, gct_part);
  gct_q<<<B_, 128, 0, stream>>>(gct_part, gp_w, gp_b, q);
  gate_max<<<dim3(NT2, B_), 256, 0, stream>>>(hmain, q, out_part);
  final_max<<<2, 256, 0, stream>>>(out_part, (float*)d_out);
}

// Round 8
// 344.059 us; speedup vs baseline: 1.1216x; 1.1216x over previous
//
#include <hip/hip_runtime.h>
#include <hip/hip_bf16.h>
#include <cmath>

// Problem constants
#define B_    4
#define T_    1000000
#define E_    8
#define C_    128
#define NCH   512        // fused conv output channels (both branches, 2*256)
#define KK    4096       // GEMM K = E * kernel (8*512); windows are contiguous rows
#define TOUT  1953       // (1e6 - 512)/512 + 1
#define TP    1956       // padded t stride (mult of 4) for aligned float4 stores
#define NT2   31         // ceil(1953/64) tiles of 64 along t

typedef __attribute__((ext_vector_type(8))) short bf16x8;   // 8 bf16 = 4 VGPRs
typedef __attribute__((ext_vector_type(4))) float f32x4;

__device__ __forceinline__ float sigmoidf_(float v) { return 1.f / (1.f + __expf(-v)); }

// ---------------------------------------------------------------------------
// Fragment-ordered operand layout ("frag chunk" = 16 rows x 32 k, [lane][8] in
// exact MFMA operand order: lane = (k>>3 & 3)*16 + (row&15), j = k&7). One
// chunk = 512 elems = 1KB; a fragment load = ONE coalesced dwordx4 per lane.
// xb2: [b][tt=t/16][kc=k/32][lane][8]   (2^23 elements per batch, t zero-pad)
// Wn2: [nt=n/16][kc][lane][8]
//
// Kernel A: merged input prep (R6-proven).
//  - blocks [0,512): weight prep for channel n (LDS transpose (e,kpos)->k)
//  - blocks [512, 512+16384): x fp32 -> bf16 frag-ordered, zero pad t>=TOUT
__global__ __launch_bounds__(256) void prep_inputs(
    const float* __restrict__ x,
    const float* __restrict__ wc, const float* __restrict__ bc,
    const float* __restrict__ wm, const float* __restrict__ bm,
    __hip_bfloat16* __restrict__ xb2, __hip_bfloat16* __restrict__ Wn2,
    float* __restrict__ bias_t) {
  __shared__ float row[KK];
  const int bid = blockIdx.x;
  if (bid < NCH) {
    const int n = bid, br = n >> 8, o = n & 255;
    const float* wsrc = (br ? wm : wc) + (size_t)o * KK;
    for (int i = threadIdx.x; i < KK; i += 256) row[i] = wsrc[i];   // [e][kpos]
    __syncthreads();
    const int nt = n >> 4, nr = n & 15;
    for (int k = threadIdx.x; k < KK; k += 256) {
      int kpos = k >> 3, e = k & 7;                 // W[n][k] with k = kpos*8+e
      size_t addr = (((size_t)nt * 128 + (k >> 5)) * 64
                     + (size_t)((k >> 3) & 3) * 16 + nr) * 8 + (k & 7);
      Wn2[addr] = __float2bfloat16(row[e * 512 + kpos]);
    }
    if (threadIdx.x == 0) bias_t[n] = (br ? bm : bc)[o];
  } else {
    size_t gid = (size_t)(bid - NCH) * 256 + threadIdx.x;
    size_t idx8 = gid * 8;                       // element index in [4][2^23]
    size_t b = idx8 >> 23, rem = idx8 & ((1ull << 23) - 1);
    int lane = (int)((rem >> 3) & 63);
    int kc   = (int)((rem >> 9) & 127);
    int tt   = (int)(rem >> 16);
    int t = tt * 16 + (lane & 15);
    int k = kc * 32 + (lane >> 4) * 8;
    union { __hip_bfloat16 h[8]; uint4 u; } o;
    if (t < TOUT) {
      const float* src = x + b * 8000000ull + (size_t)t * KK + k;
      float4 f0 = *(const float4*)(src);
      float4 f1 = *(const float4*)(src + 4);
      o.h[0] = __float2bfloat16(f0.x); o.h[1] = __float2bfloat16(f0.y);
      o.h[2] = __float2bfloat16(f0.z); o.h[3] = __float2bfloat16(f0.w);
      o.h[4] = __float2bfloat16(f1.x); o.h[5] = __float2bfloat16(f1.y);
      o.h[6] = __float2bfloat16(f1.z); o.h[7] = __float2bfloat16(f1.w);
    } else {
      o.u = make_uint4(0, 0, 0, 0);
    }
    *(uint4*)(xb2 + idx8) = o.u;
  }
}

// ---------------------------------------------------------------------------
// Kernel C: barrier-free, LDS-free register GEMM on pre-fragmented operands
// (R6 structure). New shape for TLP: block = 512 thr = 8 waves (2t x 4n),
// block tile 64t x 128n, wave tile 32t x 32n. Grid 512 = 2 blocks/CU =
// 4 waves/SIMD (vs R6's 2). Every frag load = 1 coalesced dwordx4/lane.
// XCD swizzle: 4 n-groups of one (t,b) share L%8 = XCD (R4 proof).
__global__ __launch_bounds__(512, 2) void mfma_gemm(
    const __hip_bfloat16* __restrict__ xb2, const __hip_bfloat16* __restrict__ Wn2,
    float* __restrict__ u2) {
  const int tid  = threadIdx.x;
  const int lane = tid & 63, wave = tid >> 6;
  const int wt = wave & 1, wn = wave >> 1;     // 2 t-waves x 4 n-waves

  // Swizzle: L = xcd + 8*nb + 32*g; s = g*8 + xcd in [0,128).
  const int L   = blockIdx.x;
  const int xcd = L & 7;
  const int nb  = (L >> 3) & 3;
  const int g   = L >> 5;                 // 0..15
  const int s   = g * 8 + xcd;            // 0..127
  const int tblk = s & 31, b = s >> 5;    // 32 t-tiles of 64 x 4 batches
  const int t0 = tblk * 64, n0 = nb * 128;

  const size_t FR = 512;                  // elems per frag chunk
  const __hip_bfloat16* aB = xb2
      + ((size_t)(b * 128 + tblk * 4 + wt * 2) * 128) * FR + (size_t)lane * 8;
  const __hip_bfloat16* bB = Wn2
      + ((size_t)(nb * 8 + wn * 2) * 128) * FR + (size_t)lane * 8;
  // A frag (i,kc) at aB + (i*128+kc)*FR ; B frag (j,kc) at bB + (j*128+kc)*FR

  f32x4 acc[2][2];
#pragma unroll
  for (int i = 0; i < 2; ++i)
#pragma unroll
    for (int j = 0; j < 2; ++j) acc[i][j] = (f32x4)(0.0f);

  bf16x8 A0[2][2], B0[2][2], A1[2][2], B1[2][2];

  auto load_set = [&](bf16x8 (&aF)[2][2], bf16x8 (&bF)[2][2], int kc) {
#pragma unroll
    for (int i = 0; i < 2; ++i)
#pragma unroll
      for (int c = 0; c < 2; ++c)
        aF[i][c] = *(const bf16x8*)(aB + (size_t)(i * 128 + kc + c) * FR);
#pragma unroll
    for (int j = 0; j < 2; ++j)
#pragma unroll
      for (int c = 0; c < 2; ++c)
        bF[j][c] = *(const bf16x8*)(bB + (size_t)(j * 128 + kc + c) * FR);
  };
  auto do_mfma = [&](bf16x8 (&aF)[2][2], bf16x8 (&bF)[2][2]) {
#pragma unroll
    for (int c = 0; c < 2; ++c)
#pragma unroll
      for (int i = 0; i < 2; ++i)
#pragma unroll
        for (int j = 0; j < 2; ++j)
          acc[i][j] = __builtin_amdgcn_mfma_f32_16x16x32_bf16(aF[i][c], bF[j][c],
                                                              acc[i][j], 0, 0, 0);
  };

  load_set(A0, B0, 0);
  for (int kc = 0; kc < 128; kc += 4) {
    load_set(A1, B1, kc + 2);
    do_mfma(A0, B0);
    if (kc + 4 < 128) load_set(A0, B0, kc + 4);
    do_mfma(A1, B1);
  }

  // Epilogue. C/D layout: col = lane&15, row = (lane>>4)*4 + reg.
  const int crow = (lane >> 4) * 4;
  const int ccol = lane & 15;
#pragma unroll
  for (int j = 0; j < 2; ++j) {
    int n = n0 + wn * 32 + j * 16 + ccol;
    float* urow = u2 + ((size_t)n * B_ + b) * TP;
#pragma unroll
    for (int i = 0; i < 2; ++i) {
      int t = t0 + wt * 32 + i * 16 + crow;    // mult of 4
      if (t < TOUT) *(f32x4*)(urow + t) = acc[i][j];  // may touch pad [1953,1956)
    }
  }
}

// ---------------------------------------------------------------------------
// Kernel 2: CTX branch only. bias + GLU (on load from u2) -> 1x1 share conv +
// leaky -> per-tile max over t -> gct_part.
__global__ __launch_bounds__(256) void share_ctx(
    const float* __restrict__ u2, const float* __restrict__ bias_t,
    const float* __restrict__ wsc, const float* __restrict__ bsc,
    float* __restrict__ gct_part) {
  __shared__ float Wl[128 * 132];   // Wl[cp*132 + cout] = ws[cout, cp]
  __shared__ float ul[128 * 68];    // ul[cp*68 + t]
  const int tid  = threadIdx.x;
  const int tile = blockIdx.x;      // 0..30
  const int b    = blockIdx.y;
  const int t0   = tile * 64;

  for (int g = tid; g < 16384; g += 256) {
    int co = g >> 7, cp = g & 127;
    Wl[cp * 132 + co] = wsc[g];
  }
  const size_t base_v = (size_t)b * TP;                      // n = cp
  const size_t base_g = ((size_t)128 * B_ + b) * TP;         // n = 128+cp
  for (int g = tid; g < 8192; g += 256) {
    int cp = g >> 6, t = g & 63;
    float v = 0.f;
    if (t0 + t < TOUT) {
      float va = u2[base_v + (size_t)cp * B_ * TP + t0 + t] + bias_t[cp];
      float vg = u2[base_g + (size_t)cp * B_ * TP + t0 + t] + bias_t[128 + cp];
      v = va * sigmoidf_(vg);
    }
    ul[cp * 68 + t] = v;
  }
  __syncthreads();

  const int ty = tid >> 4, tx = tid & 15;
  float acc[8][4];
#pragma unroll
  for (int i = 0; i < 8; ++i)
#pragma unroll
    for (int j = 0; j < 4; ++j) acc[i][j] = 0.f;

  for (int cp = 0; cp < 128; ++cp) {
    float4 a0 = *(const float4*)&Wl[cp*132 + ty*4];
    float4 a1 = *(const float4*)&Wl[cp*132 + 64 + ty*4];
    float4 b4 = *(const float4*)&ul[cp*68 + tx*4];
    float av[8] = {a0.x,a0.y,a0.z,a0.w,a1.x,a1.y,a1.z,a1.w};
    float bv[4] = {b4.x,b4.y,b4.z,b4.w};
#pragma unroll
    for (int i = 0; i < 8; ++i)
#pragma unroll
      for (int j = 0; j < 4; ++j) acc[i][j] = fmaf(av[i], bv[j], acc[i][j]);
  }

  float mloc[8];
#pragma unroll
  for (int i = 0; i < 8; ++i) mloc[i] = -INFINITY;
#pragma unroll
  for (int i = 0; i < 8; ++i) {
    int c = (i < 4) ? (ty*4 + i) : (64 + ty*4 + (i - 4));
    float bias = bsc[c];
#pragma unroll
    for (int j = 0; j < 4; ++j) {
      int t = t0 + tx*4 + j;
      if (t >= TOUT) continue;
      float v = acc[i][j] + bias;
      mloc[i] = fmaxf(mloc[i], (v >= 0.f) ? v : 0.01f * v);
    }
  }
  __syncthreads();               // done reading ul; reuse as reduction buffer
#pragma unroll
  for (int i = 0; i < 8; ++i) {
    int c = (i < 4) ? (ty*4 + i) : (64 + ty*4 + (i - 4));
    ul[c * 16 + tx] = mloc[i];
  }
  __syncthreads();
  if (tid < 128) {
    float m = -INFINITY;
#pragma unroll
    for (int k = 0; k < 16; ++k) m = fmaxf(m, ul[tid * 16 + k]);
    gct_part[((size_t)b * 128 + tid) * NT2 + tile] = m;
  }
}

// ---------------------------------------------------------------------------
// Kernel 3: MAIN branch fused tail. Recomputes q in-block (gct_part -> max ->
// tanh(gct@Wp^T+bp)), computes h tile (GLU -> share conv -> leaky) in regs,
// gate[t] = sigmoid(sum_c h*q) via LDS reduce, out_part = per-tile max h*gate.
// Eliminates hmain round-trip + two launches.
__global__ __launch_bounds__(256) void share_main_gate(
    const float* __restrict__ u2, const float* __restrict__ bias_t,
    const float* __restrict__ wsm, const float* __restrict__ bsm,
    const float* __restrict__ gct_part,
    const float* __restrict__ wp, const float* __restrict__ bp,
    float* __restrict__ out_part) {
  __shared__ float Wl[128 * 132];
  __shared__ float ul[128 * 68];    // staging, then reused for reductions
  __shared__ float gbuf[128];       // gct
  __shared__ float ql[128];         // q
  const int tid  = threadIdx.x;
  const int tile = blockIdx.x;      // 0..30
  const int b    = blockIdx.y;
  const int t0   = tile * 64;

  for (int g = tid; g < 16384; g += 256) {
    int co = g >> 7, cp = g & 127;
    Wl[cp * 132 + co] = wsm[g];
  }
  const size_t base_v = ((size_t)256 * B_ + b) * TP;         // n = 256+cp
  const size_t base_g = ((size_t)384 * B_ + b) * TP;         // n = 384+cp
  for (int g = tid; g < 8192; g += 256) {
    int cp = g >> 6, t = g & 63;
    float v = 0.f;
    if (t0 + t < TOUT) {
      float va = u2[base_v + (size_t)cp * B_ * TP + t0 + t] + bias_t[256 + cp];
      float vg = u2[base_g + (size_t)cp * B_ * TP + t0 + t] + bias_t[384 + cp];
      v = va * sigmoidf_(vg);
    }
    ul[cp * 68 + t] = v;
  }
  if (tid < 128) {
    float m = -INFINITY;
    for (int tl = 0; tl < NT2; ++tl)
      m = fmaxf(m, gct_part[((size_t)b * 128 + tid) * NT2 + tl]);
    gbuf[tid] = m;
  }
  __syncthreads();
  if (tid < 128) {
    float sq = bp[tid];
    for (int c = 0; c < 128; ++c) sq = fmaf(gbuf[c], wp[tid * 128 + c], sq);
    ql[tid] = tanhf(sq);
  }

  const int ty = tid >> 4, tx = tid & 15;
  float acc[8][4];
#pragma unroll
  for (int i = 0; i < 8; ++i)
#pragma unroll
    for (int j = 0; j < 4; ++j) acc[i][j] = 0.f;

  for (int cp = 0; cp < 128; ++cp) {
    float4 a0 = *(const float4*)&Wl[cp*132 + ty*4];
    float4 a1 = *(const float4*)&Wl[cp*132 + 64 + ty*4];
    float4 b4 = *(const float4*)&ul[cp*68 + tx*4];
    float av[8] = {a0.x,a0.y,a0.z,a0.w,a1.x,a1.y,a1.z,a1.w};
    float bv[4] = {b4.x,b4.y,b4.z,b4.w};
#pragma unroll
    for (int i = 0; i < 8; ++i)
#pragma unroll
      for (int j = 0; j < 4; ++j) acc[i][j] = fmaf(av[i], bv[j], acc[i][j]);
  }

  // h = leaky(acc + bias) in regs; c_i = (i<4) ? ty*4+i : 64+ty*4+(i-4)
  float h[8][4];
#pragma unroll
  for (int i = 0; i < 8; ++i) {
    int c = (i < 4) ? (ty*4 + i) : (64 + ty*4 + (i - 4));
    float bias = bsm[c];
#pragma unroll
    for (int j = 0; j < 4; ++j) {
      float v = acc[i][j] + bias;
      h[i][j] = (v >= 0.f) ? v : 0.01f * v;
    }
  }
  __syncthreads();   // ul free for reuse; ql visible to all

  // gate partials: pg[j] = sum_i h[i][j] * q[c_i]  -> ul[t*16 + ty]
#pragma unroll
  for (int j = 0; j < 4; ++j) {
    float pg = 0.f;
#pragma unroll
    for (int i = 0; i < 8; ++i) {
      int c = (i < 4) ? (ty*4 + i) : (64 + ty*4 + (i - 4));
      pg = fmaf(h[i][j], ql[c], pg);
    }
    ul[(tx*4 + j) * 16 + ty] = pg;
  }
  __syncthreads();
  if (tid < 64) {
    float sg = 0.f;
#pragma unroll
    for (int y = 0; y < 16; ++y) sg += ul[tid * 16 + y];
    ul[1024 + tid] = sigmoidf_(sg);    // gate[t]
  }
  __syncthreads();

  // per-c max over this tile's t of h*gate -> ul[2048 + c*16 + tx]
#pragma unroll
  for (int i = 0; i < 8; ++i) {
    int c = (i < 4) ? (ty*4 + i) : (64 + ty*4 + (i - 4));
    float m = -INFINITY;
#pragma unroll
    for (int j = 0; j < 4; ++j) {
      int t = t0 + tx*4 + j;
      if (t < TOUT) m = fmaxf(m, h[i][j] * ul[1024 + tx*4 + j]);
    }
    ul[2048 + c * 16 + tx] = m;
  }
  __syncthreads();
  if (tid < 128) {
    float m = -INFINITY;
#pragma unroll
    for (int k = 0; k < 16; ++k) m = fmaxf(m, ul[2048 + tid * 16 + k]);
    out_part[((size_t)b * 128 + tid) * NT2 + tile] = m;
  }
}

// ---------------------------------------------------------------------------
// Kernel 4: final max over tiles -> d_out (B,C) row-major.
__global__ void final_max(const float* __restrict__ out_part, float* __restrict__ out) {
  int idx = blockIdx.x * 256 + threadIdx.x;
  if (idx < 512) {
    float m = -INFINITY;
    for (int tl = 0; tl < NT2; ++tl) m = fmaxf(m, out_part[(size_t)idx * NT2 + tl]);
    out[idx] = m;
  }
}

// ---------------------------------------------------------------------------
extern "C" void kernel_launch(void* const* d_in, const int* in_sizes, int n_in,
                              void* d_out, int out_size, void* d_ws, size_t ws_size,
                              hipStream_t stream) {
  const float* x      = (const float*)d_in[0];
  const float* ctx_w  = (const float*)d_in[1];
  const float* ctx_b  = (const float*)d_in[2];
  const float* ctx_sw = (const float*)d_in[3];
  const float* ctx_sb = (const float*)d_in[4];
  const float* main_w = (const float*)d_in[5];
  const float* main_b = (const float*)d_in[6];
  const float* main_sw= (const float*)d_in[7];
  const float* main_sb= (const float*)d_in[8];
  const float* gp_w   = (const float*)d_in[9];
  const float* gp_b   = (const float*)d_in[10];

  char* w = (char*)d_ws;
  __hip_bfloat16* xb2 = (__hip_bfloat16*)(w);              // 4*2^23*2   = 67,108,864
  __hip_bfloat16* Wn2 = (__hip_bfloat16*)(w + 67108864);   // 512*4096*2 =  4,194,304
  float* bias_t  = (float*)(w + 71303168);                 // 512*4
  float* u2      = (float*)(w + 71305216);                 // 512*4*TP*4 = 16,023,552
  float* gct_part= (float*)(w + 87328768);                 // 4*128*31*4 = 63,488
  float* out_part= (float*)(w + 87392256);                 // 63,488

  prep_inputs<<<NCH + 16384, 256, 0, stream>>>(x, ctx_w, ctx_b, main_w, main_b,
                                               xb2, Wn2, bias_t);
  mfma_gemm<<<512, 512, 0, stream>>>(xb2, Wn2, u2);
  share_ctx<<<dim3(NT2, B_), 256, 0, stream>>>(u2, bias_t, ctx_sw, ctx_sb, gct_part);
  share_main_gate<<<dim3(NT2, B_), 256, 0, stream>>>(u2, bias_t, main_sw, main_sb,
                                                     gct_part, gp_w, gp_b, out_part);
  final_max<<<2, 256, 0, stream>>>(out_part, (float*)d_out);
}

// Round 9
// 329.768 us; speedup vs baseline: 1.1702x; 1.0433x over previous
//
#include <hip/hip_runtime.h>
#include <hip/hip_bf16.h>
#include <cmath>

// Problem constants
#define B_    4
#define T_    1000000
#define E_    8
#define C_    128
#define NCH   512        // fused conv output channels (both branches, 2*256)
#define KK    4096       // GEMM K = E * kernel (8*512); windows are contiguous rows
#define TOUT  1953       // (1e6 - 512)/512 + 1
#define TP    1956       // padded t stride (mult of 4) for aligned float4 stores
#define NT2   31         // ceil(1953/64) tiles of 64 along t

typedef __attribute__((ext_vector_type(8))) short bf16x8;   // 8 bf16 = 4 VGPRs
typedef __attribute__((ext_vector_type(4))) float f32x4;

__device__ __forceinline__ float sigmoidf_(float v) { return 1.f / (1.f + __expf(-v)); }

// ---------------------------------------------------------------------------
// Fragment-ordered operand layout ("frag chunk" = 16 rows x 32 k, [lane][8] in
// exact MFMA operand order: lane = (k>>3 & 3)*16 + (row&15), j = k&7). One
// chunk = 512 elems = 1KB; a fragment load = ONE coalesced dwordx4 per lane.
// xb2: [b][tt=t/16][kc=k/32][lane][8]   (2^23 elements per batch, t zero-pad)
// Wn2: [nt=n/16][kc][lane][8]
//
// Kernel A: merged input prep (R6-proven).
__global__ __launch_bounds__(256) void prep_inputs(
    const float* __restrict__ x,
    const float* __restrict__ wc, const float* __restrict__ bc,
    const float* __restrict__ wm, const float* __restrict__ bm,
    __hip_bfloat16* __restrict__ xb2, __hip_bfloat16* __restrict__ Wn2,
    float* __restrict__ bias_t) {
  __shared__ float row[KK];
  const int bid = blockIdx.x;
  if (bid < NCH) {
    const int n = bid, br = n >> 8, o = n & 255;
    const float* wsrc = (br ? wm : wc) + (size_t)o * KK;
    for (int i = threadIdx.x; i < KK; i += 256) row[i] = wsrc[i];   // [e][kpos]
    __syncthreads();
    const int nt = n >> 4, nr = n & 15;
    for (int k = threadIdx.x; k < KK; k += 256) {
      int kpos = k >> 3, e = k & 7;                 // W[n][k] with k = kpos*8+e
      size_t addr = (((size_t)nt * 128 + (k >> 5)) * 64
                     + (size_t)((k >> 3) & 3) * 16 + nr) * 8 + (k & 7);
      Wn2[addr] = __float2bfloat16(row[e * 512 + kpos]);
    }
    if (threadIdx.x == 0) bias_t[n] = (br ? bm : bc)[o];
  } else {
    size_t gid = (size_t)(bid - NCH) * 256 + threadIdx.x;
    size_t idx8 = gid * 8;                       // element index in [4][2^23]
    size_t b = idx8 >> 23, rem = idx8 & ((1ull << 23) - 1);
    int lane = (int)((rem >> 3) & 63);
    int kc   = (int)((rem >> 9) & 127);
    int tt   = (int)(rem >> 16);
    int t = tt * 16 + (lane & 15);
    int k = kc * 32 + (lane >> 4) * 8;
    union { __hip_bfloat16 h[8]; uint4 u; } o;
    if (t < TOUT) {
      const float* src = x + b * 8000000ull + (size_t)t * KK + k;
      float4 f0 = *(const float4*)(src);
      float4 f1 = *(const float4*)(src + 4);
      o.h[0] = __float2bfloat16(f0.x); o.h[1] = __float2bfloat16(f0.y);
      o.h[2] = __float2bfloat16(f0.z); o.h[3] = __float2bfloat16(f0.w);
      o.h[4] = __float2bfloat16(f1.x); o.h[5] = __float2bfloat16(f1.y);
      o.h[6] = __float2bfloat16(f1.z); o.h[7] = __float2bfloat16(f1.w);
    } else {
      o.u = make_uint4(0, 0, 0, 0);
    }
    *(uint4*)(xb2 + idx8) = o.u;
  }
}

// ---------------------------------------------------------------------------
// Kernel C: barrier-free, LDS-free register GEMM — EXACT R6 shape (proven
// ~40us): block = 512 thr = 8 waves (4 t-waves x 2 n-waves), block tile
// 128x128, wave tile 32t x 64n (12 loads feed 16 MFMAs per 2-chunk set).
// Grid 256 = 1 block/CU. XCD swizzle: 4 n-groups of one (t,b) share L%8 =
// XCD so A re-reads hit that XCD's L2 (R4 proof: FETCH 254->82MB).
// R8's 32x32-wave/2-blocks-per-CU variant was 2x slower — per-wave
// arithmetic intensity beats TLP here.
__global__ __launch_bounds__(512, 2) void mfma_gemm(
    const __hip_bfloat16* __restrict__ xb2, const __hip_bfloat16* __restrict__ Wn2,
    float* __restrict__ u2) {
  const int tid  = threadIdx.x;
  const int lane = tid & 63, wave = tid >> 6;
  const int wt = wave & 3, wn = wave >> 2;

  // Swizzle: L = xcd + 8*(nb + 4*sh); s = sh*8 + xcd = (t,b) group 0..63.
  const int L   = blockIdx.x;
  const int xcd = L & 7;
  const int r   = L >> 3;
  const int nb  = r & 3;
  const int sh  = r >> 2;                 // 0..7
  const int s   = sh * 8 + xcd;           // 0..63
  const int tblk = s & 15, b = s >> 4;
  const int t0 = tblk * 128, n0 = nb * 128;

  const size_t FR = 512;                  // elems per frag chunk
  const __hip_bfloat16* aB = xb2
      + ((size_t)(b * 128 + (t0 >> 4) + wt * 2) * 128) * FR + (size_t)lane * 8;
  const __hip_bfloat16* bB = Wn2
      + ((size_t)((n0 >> 4) + wn * 4) * 128) * FR + (size_t)lane * 8;
  // A frag (i,kc) at aB + (i*128+kc)*FR ; B frag (j,kc) at bB + (j*128+kc)*FR

  f32x4 acc[2][4];
#pragma unroll
  for (int i = 0; i < 2; ++i)
#pragma unroll
    for (int j = 0; j < 4; ++j) acc[i][j] = (f32x4)(0.0f);

  bf16x8 A0[2][2], B0[4][2], A1[2][2], B1[4][2];

  auto load_set = [&](bf16x8 (&aF)[2][2], bf16x8 (&bF)[4][2], int kc) {
#pragma unroll
    for (int i = 0; i < 2; ++i)
#pragma unroll
      for (int c = 0; c < 2; ++c)
        aF[i][c] = *(const bf16x8*)(aB + (size_t)(i * 128 + kc + c) * FR);
#pragma unroll
    for (int j = 0; j < 4; ++j)
#pragma unroll
      for (int c = 0; c < 2; ++c)
        bF[j][c] = *(const bf16x8*)(bB + (size_t)(j * 128 + kc + c) * FR);
  };
  auto do_mfma = [&](bf16x8 (&aF)[2][2], bf16x8 (&bF)[4][2]) {
#pragma unroll
    for (int c = 0; c < 2; ++c)
#pragma unroll
      for (int i = 0; i < 2; ++i)
#pragma unroll
        for (int j = 0; j < 4; ++j)
          acc[i][j] = __builtin_amdgcn_mfma_f32_16x16x32_bf16(aF[i][c], bF[j][c],
                                                              acc[i][j], 0, 0, 0);
  };

  load_set(A0, B0, 0);
  for (int kc = 0; kc < 128; kc += 4) {
    load_set(A1, B1, kc + 2);
    do_mfma(A0, B0);
    if (kc + 4 < 128) load_set(A0, B0, kc + 4);
    do_mfma(A1, B1);
  }

  // Epilogue. C/D layout: col = lane&15, row = (lane>>4)*4 + reg.
  const int crow = (lane >> 4) * 4;
  const int ccol = lane & 15;
#pragma unroll
  for (int j = 0; j < 4; ++j) {
    int n = n0 + wn * 64 + j * 16 + ccol;
    float* urow = u2 + ((size_t)n * B_ + b) * TP;
#pragma unroll
    for (int i = 0; i < 2; ++i) {
      int t = t0 + wt * 32 + i * 16 + crow;    // mult of 4
      if (t < TOUT) *(f32x4*)(urow + t) = acc[i][j];  // may touch pad [1953,1956)
    }
  }
}

// ---------------------------------------------------------------------------
// Kernel 2: CTX branch only. bias + GLU (on load from u2) -> 1x1 share conv +
// leaky -> per-tile max over t -> gct_part.
__global__ __launch_bounds__(256) void share_ctx(
    const float* __restrict__ u2, const float* __restrict__ bias_t,
    const float* __restrict__ wsc, const float* __restrict__ bsc,
    float* __restrict__ gct_part) {
  __shared__ float Wl[128 * 132];   // Wl[cp*132 + cout] = ws[cout, cp]
  __shared__ float ul[128 * 68];    // ul[cp*68 + t]
  const int tid  = threadIdx.x;
  const int tile = blockIdx.x;      // 0..30
  const int b    = blockIdx.y;
  const int t0   = tile * 64;

  for (int g = tid; g < 16384; g += 256) {
    int co = g >> 7, cp = g & 127;
    Wl[cp * 132 + co] = wsc[g];
  }
  const size_t base_v = (size_t)b * TP;                      // n = cp
  const size_t base_g = ((size_t)128 * B_ + b) * TP;         // n = 128+cp
  for (int g = tid; g < 8192; g += 256) {
    int cp = g >> 6, t = g & 63;
    float v = 0.f;
    if (t0 + t < TOUT) {
      float va = u2[base_v + (size_t)cp * B_ * TP + t0 + t] + bias_t[cp];
      float vg = u2[base_g + (size_t)cp * B_ * TP + t0 + t] + bias_t[128 + cp];
      v = va * sigmoidf_(vg);
    }
    ul[cp * 68 + t] = v;
  }
  __syncthreads();

  const int ty = tid >> 4, tx = tid & 15;
  float acc[8][4];
#pragma unroll
  for (int i = 0; i < 8; ++i)
#pragma unroll
    for (int j = 0; j < 4; ++j) acc[i][j] = 0.f;

  for (int cp = 0; cp < 128; ++cp) {
    float4 a0 = *(const float4*)&Wl[cp*132 + ty*4];
    float4 a1 = *(const float4*)&Wl[cp*132 + 64 + ty*4];
    float4 b4 = *(const float4*)&ul[cp*68 + tx*4];
    float av[8] = {a0.x,a0.y,a0.z,a0.w,a1.x,a1.y,a1.z,a1.w};
    float bv[4] = {b4.x,b4.y,b4.z,b4.w};
#pragma unroll
    for (int i = 0; i < 8; ++i)
#pragma unroll
      for (int j = 0; j < 4; ++j) acc[i][j] = fmaf(av[i], bv[j], acc[i][j]);
  }

  float mloc[8];
#pragma unroll
  for (int i = 0; i < 8; ++i) mloc[i] = -INFINITY;
#pragma unroll
  for (int i = 0; i < 8; ++i) {
    int c = (i < 4) ? (ty*4 + i) : (64 + ty*4 + (i - 4));
    float bias = bsc[c];
#pragma unroll
    for (int j = 0; j < 4; ++j) {
      int t = t0 + tx*4 + j;
      if (t >= TOUT) continue;
      float v = acc[i][j] + bias;
      mloc[i] = fmaxf(mloc[i], (v >= 0.f) ? v : 0.01f * v);
    }
  }
  __syncthreads();               // done reading ul; reuse as reduction buffer
#pragma unroll
  for (int i = 0; i < 8; ++i) {
    int c = (i < 4) ? (ty*4 + i) : (64 + ty*4 + (i - 4));
    ul[c * 16 + tx] = mloc[i];
  }
  __syncthreads();
  if (tid < 128) {
    float m = -INFINITY;
#pragma unroll
    for (int k = 0; k < 16; ++k) m = fmaxf(m, ul[tid * 16 + k]);
    gct_part[((size_t)b * 128 + tid) * NT2 + tile] = m;
  }
}

// ---------------------------------------------------------------------------
// Kernel 3: MAIN branch fused tail. Recomputes q in-block (gct_part -> max ->
// tanh(gct@Wp^T+bp)), computes h tile (GLU -> share conv -> leaky) in regs,
// gate[t] = sigmoid(sum_c h*q) via LDS reduce, out_part = per-tile max h*gate.
__global__ __launch_bounds__(256) void share_main_gate(
    const float* __restrict__ u2, const float* __restrict__ bias_t,
    const float* __restrict__ wsm, const float* __restrict__ bsm,
    const float* __restrict__ gct_part,
    const float* __restrict__ wp, const float* __restrict__ bp,
    float* __restrict__ out_part) {
  __shared__ float Wl[128 * 132];
  __shared__ float ul[128 * 68];    // staging, then reused for reductions
  __shared__ float gbuf[128];       // gct
  __shared__ float ql[128];         // q
  const int tid  = threadIdx.x;
  const int tile = blockIdx.x;      // 0..30
  const int b    = blockIdx.y;
  const int t0   = tile * 64;

  for (int g = tid; g < 16384; g += 256) {
    int co = g >> 7, cp = g & 127;
    Wl[cp * 132 + co] = wsm[g];
  }
  const size_t base_v = ((size_t)256 * B_ + b) * TP;         // n = 256+cp
  const size_t base_g = ((size_t)384 * B_ + b) * TP;         // n = 384+cp
  for (int g = tid; g < 8192; g += 256) {
    int cp = g >> 6, t = g & 63;
    float v = 0.f;
    if (t0 + t < TOUT) {
      float va = u2[base_v + (size_t)cp * B_ * TP + t0 + t] + bias_t[256 + cp];
      float vg = u2[base_g + (size_t)cp * B_ * TP + t0 + t] + bias_t[384 + cp];
      v = va * sigmoidf_(vg);
    }
    ul[cp * 68 + t] = v;
  }
  if (tid < 128) {
    float m = -INFINITY;
    for (int tl = 0; tl < NT2; ++tl)
      m = fmaxf(m, gct_part[((size_t)b * 128 + tid) * NT2 + tl]);
    gbuf[tid] = m;
  }
  __syncthreads();
  if (tid < 128) {
    float sq = bp[tid];
    for (int c = 0; c < 128; ++c) sq = fmaf(gbuf[c], wp[tid * 128 + c], sq);
    ql[tid] = tanhf(sq);
  }

  const int ty = tid >> 4, tx = tid & 15;
  float acc[8][4];
#pragma unroll
  for (int i = 0; i < 8; ++i)
#pragma unroll
    for (int j = 0; j < 4; ++j) acc[i][j] = 0.f;

  for (int cp = 0; cp < 128; ++cp) {
    float4 a0 = *(const float4*)&Wl[cp*132 + ty*4];
    float4 a1 = *(const float4*)&Wl[cp*132 + 64 + ty*4];
    float4 b4 = *(const float4*)&ul[cp*68 + tx*4];
    float av[8] = {a0.x,a0.y,a0.z,a0.w,a1.x,a1.y,a1.z,a1.w};
    float bv[4] = {b4.x,b4.y,b4.z,b4.w};
#pragma unroll
    for (int i = 0; i < 8; ++i)
#pragma unroll
      for (int j = 0; j < 4; ++j) acc[i][j] = fmaf(av[i], bv[j], acc[i][j]);
  }

  // h = leaky(acc + bias) in regs; c_i = (i<4) ? ty*4+i : 64+ty*4+(i-4)
  float h[8][4];
#pragma unroll
  for (int i = 0; i < 8; ++i) {
    int c = (i < 4) ? (ty*4 + i) : (64 + ty*4 + (i - 4));
    float bias = bsm[c];
#pragma unroll
    for (int j = 0; j < 4; ++j) {
      float v = acc[i][j] + bias;
      h[i][j] = (v >= 0.f) ? v : 0.01f * v;
    }
  }
  __syncthreads();   // ul free for reuse; ql visible to all

  // gate partials: pg[j] = sum_i h[i][j] * q[c_i]  -> ul[t*16 + ty]
#pragma unroll
  for (int j = 0; j < 4; ++j) {
    float pg = 0.f;
#pragma unroll
    for (int i = 0; i < 8; ++i) {
      int c = (i < 4) ? (ty*4 + i) : (64 + ty*4 + (i - 4));
      pg = fmaf(h[i][j], ql[c], pg);
    }
    ul[(tx*4 + j) * 16 + ty] = pg;
  }
  __syncthreads();
  if (tid < 64) {
    float sg = 0.f;
#pragma unroll
    for (int y = 0; y < 16; ++y) sg += ul[tid * 16 + y];
    ul[1024 + tid] = sigmoidf_(sg);    // gate[t]
  }
  __syncthreads();

  // per-c max over this tile's t of h*gate -> ul[2048 + c*16 + tx]
#pragma unroll
  for (int i = 0; i < 8; ++i) {
    int c = (i < 4) ? (ty*4 + i) : (64 + ty*4 + (i - 4));
    float m = -INFINITY;
#pragma unroll
    for (int j = 0; j < 4; ++j) {
      int t = t0 + tx*4 + j;
      if (t < TOUT) m = fmaxf(m, h[i][j] * ul[1024 + tx*4 + j]);
    }
    ul[2048 + c * 16 + tx] = m;
  }
  __syncthreads();
  if (tid < 128) {
    float m = -INFINITY;
#pragma unroll
    for (int k = 0; k < 16; ++k) m = fmaxf(m, ul[2048 + tid * 16 + k]);
    out_part[((size_t)b * 128 + tid) * NT2 + tile] = m;
  }
}

// ---------------------------------------------------------------------------
// Kernel 4: final max over tiles -> d_out (B,C) row-major.
__global__ void final_max(const float* __restrict__ out_part, float* __restrict__ out) {
  int idx = blockIdx.x * 256 + threadIdx.x;
  if (idx < 512) {
    float m = -INFINITY;
    for (int tl = 0; tl < NT2; ++tl) m = fmaxf(m, out_part[(size_t)idx * NT2 + tl]);
    out[idx] = m;
  }
}

// ---------------------------------------------------------------------------
extern "C" void kernel_launch(void* const* d_in, const int* in_sizes, int n_in,
                              void* d_out, int out_size, void* d_ws, size_t ws_size,
                              hipStream_t stream) {
  const float* x      = (const float*)d_in[0];
  const float* ctx_w  = (const float*)d_in[1];
  const float* ctx_b  = (const float*)d_in[2];
  const float* ctx_sw = (const float*)d_in[3];
  const float* ctx_sb = (const float*)d_in[4];
  const float* main_w = (const float*)d_in[5];
  const float* main_b = (const float*)d_in[6];
  const float* main_sw= (const float*)d_in[7];
  const float* main_sb= (const float*)d_in[8];
  const float* gp_w   = (const float*)d_in[9];
  const float* gp_b   = (const float*)d_in[10];

  char* w = (char*)d_ws;
  __hip_bfloat16* xb2 = (__hip_bfloat16*)(w);              // 4*2^23*2   = 67,108,864
  __hip_bfloat16* Wn2 = (__hip_bfloat16*)(w + 67108864);   // 512*4096*2 =  4,194,304
  float* bias_t  = (float*)(w + 71303168);                 // 512*4
  float* u2      = (float*)(w + 71305216);                 // 512*4*TP*4 = 16,023,552
  float* gct_part= (float*)(w + 87328768);                 // 4*128*31*4 = 63,488
  float* out_part= (float*)(w + 87392256);                 // 63,488

  prep_inputs<<<NCH + 16384, 256, 0, stream>>>(x, ctx_w, ctx_b, main_w, main_b,
                                               xb2, Wn2, bias_t);
  mfma_gemm<<<256, 512, 0, stream>>>(xb2, Wn2, u2);
  share_ctx<<<dim3(NT2, B_), 256, 0, stream>>>(u2, bias_t, ctx_sw, ctx_sb, gct_part);
  share_main_gate<<<dim3(NT2, B_), 256, 0, stream>>>(u2, bias_t, main_sw, main_sb,
                                                     gct_part, gp_w, gp_b, out_part);
  final_max<<<2, 256, 0, stream>>>(out_part, (float*)d_out);
}